// Round 6
// baseline (483.295 us; speedup 1.0000x reference)
//
#include <hip/hip_runtime.h>
#include <hip/hip_fp16.h>
#include <stdint.h>

#define TOK 8192      // B*S
#define DIM 1024
#define NE 8
#define NT 72         // max 256-row tiles: 64 full + <=7 ragged (+1 safety)
#define NCT 4         // 1024 / 256 col-tiles

typedef short bf16x8 __attribute__((ext_vector_type(8)));
typedef float f32x4 __attribute__((ext_vector_type(4)));

__device__ __forceinline__ unsigned short f2bf(float f) {
  unsigned int u = __float_as_uint(f);
  u += 0x7FFFu + ((u >> 16) & 1u);
  return (unsigned short)(u >> 16);
}

__device__ __forceinline__ void gl_lds16(const void* g, void* l) {
  __builtin_amdgcn_global_load_lds(
      (__attribute__((address_space(1))) unsigned int*)(g),
      (__attribute__((address_space(3))) unsigned int*)(l), 16, 0, 0);
}

__device__ __forceinline__ unsigned lds_off(const void* p) {
  // generic -> LDS(AS3) pointer -> 32-bit LDS byte offset
  return (unsigned)(size_t)(__attribute__((address_space(3))) const void*)p;
}

// R12: gate and transpose_w are independent memory-bound kernels -> fused
// into one dispatch (blockIdx-uniform branch, 32KB LDS union). Blocks
// 0..2047: gate (1 wave/token); 2048..4095: W transpose 64x64 tiles.
__global__ __launch_bounds__(256) void gate_transpose(
    const float* __restrict__ x, const float* __restrict__ gW,
    const float* __restrict__ gb, unsigned short* __restrict__ xb,
    int* __restrict__ eSel, float* __restrict__ wSel, int* __restrict__ cnt,
    const float* __restrict__ W, unsigned short* __restrict__ Wt)
{
  __shared__ __align__(16) float smem[NE * DIM];   // 32 KB union

  if (blockIdx.x >= 2048) {
    // ---- transpose_w branch: expert_W [e][d][f] fp32 -> Wt [e][f][d] bf16
    float (*t2)[65] = (float(*)[65])smem;          // 64 x 65 padded
    const int b  = blockIdx.x - 2048;
    const int e  = b >> 8;                 // 256 tiles per expert
    const int db = (b >> 4) & 15;          // d (k) block
    const int fb = b & 15;                 // f block
    const int d0 = db * 64, f0 = fb * 64;
    const int tid = threadIdx.x;
#pragma unroll
    for (int h = 0; h < 4; ++h) {
      const int idx = tid + h * 256;
      const int r = idx >> 4, c4 = idx & 15;
      float4 v = *(const float4*)&W[((size_t)e * DIM + d0 + r) * DIM + f0 + c4 * 4];
      t2[r][c4 * 4 + 0] = v.x;
      t2[r][c4 * 4 + 1] = v.y;
      t2[r][c4 * 4 + 2] = v.z;
      t2[r][c4 * 4 + 3] = v.w;
    }
    __syncthreads();
#pragma unroll
    for (int h = 0; h < 8; ++h) {
      const int o = tid + h * 256;
      const int f = o >> 5, k2 = (o & 31) * 2;
      const unsigned int lo = f2bf(t2[k2][f]);
      const unsigned int hi = f2bf(t2[k2 + 1][f]);
      *(unsigned int*)&Wt[((size_t)e * DIM + f0 + f) * DIM + d0 + k2] =
          lo | (hi << 16);
    }
    return;
  }

  // ---- gate branch: x row -> bf16 + gating dots (fp64 acc) + top-2 picks
  if (blockIdx.x == 0 && threadIdx.x < NE) cnt[threadIdx.x] = 0;

  float* gWs = smem;                // [e][d], 32 KB
#pragma unroll
  for (int h = 0; h < 8; ++h) {
    const int m = threadIdx.x + h * 256;       // float4 id over gW (2048)
    float4 v = ((const float4*)gW)[m];
    const int d = m >> 1, e0 = (m & 1) * 4;    // gW is [d][e]
    gWs[(e0 + 0) * DIM + d] = v.x;
    gWs[(e0 + 1) * DIM + d] = v.y;
    gWs[(e0 + 2) * DIM + d] = v.z;
    gWs[(e0 + 3) * DIM + d] = v.w;
  }
  __syncthreads();

  const int wave = threadIdx.x >> 6;
  const int lane = threadIdx.x & 63;
  const int t = blockIdx.x * 4 + wave;
  const float4* xrow = (const float4*)(x + (size_t)t * DIM);
  ushort4* xbrow = (ushort4*)(xb + (size_t)t * DIM);

  double acc[NE];
#pragma unroll
  for (int e = 0; e < NE; ++e) acc[e] = 0.0;

#pragma unroll
  for (int i = 0; i < 4; ++i) {
    const int j = i * 64 + lane;         // float4 index within row (0..255)
    float4 v = xrow[j];
    ushort4 pk;
    pk.x = f2bf(v.x); pk.y = f2bf(v.y); pk.z = f2bf(v.z); pk.w = f2bf(v.w);
    xbrow[j] = pk;
#pragma unroll
    for (int e = 0; e < NE; ++e) {
      float4 gv = *(const float4*)&gWs[e * DIM + j * 4];
      acc[e] += (double)v.x * (double)gv.x + (double)v.y * (double)gv.y
              + (double)v.z * (double)gv.z + (double)v.w * (double)gv.w;
    }
  }
#pragma unroll
  for (int off = 32; off > 0; off >>= 1) {
#pragma unroll
    for (int e = 0; e < NE; ++e)
      acc[e] += __shfl_xor(acc[e], off, 64);
  }

  if (lane == 0) {
    double s[NE];
#pragma unroll
    for (int e = 0; e < NE; ++e) {
      s[e] = acc[e] + (double)gb[e];
      if (s[e] < 1e-4) s[e] = 1e-4;     // clamp-min(EPS), TEMP=1
    }
    int e0 = 0;
    for (int e = 1; e < NE; ++e) if (s[e] > s[e0]) e0 = e;
    int e1 = (e0 == 0) ? 1 : 0;
    for (int e = 0; e < NE; ++e) if (e != e0 && s[e] > s[e1]) e1 = e;
    float m = (float)s[e0];
    float Z = 0.f, pf[NE];
#pragma unroll
    for (int e = 0; e < NE; ++e) { pf[e] = __expf((float)s[e] - m); Z += pf[e]; }
    float w0 = pf[e0] / Z; if (w0 < 0.1f) w0 = 0.1f;
    float w1 = pf[e1] / Z; if (w1 < 0.1f) w1 = 0.1f;
    const float inv = 0.5f / (w0 + w1);   // /total /K
    eSel[t * 2 + 0] = e0;
    eSel[t * 2 + 1] = e1;
    wSel[t * 2 + 0] = w0 * inv;
    wSel[t * 2 + 1] = w1 * inv;
  }
}

// Two-level scatter: LDS histogram per block, 8 global atomics per block.
__global__ __launch_bounds__(256) void scatter_kernel(
    const int* __restrict__ eSel, const float* __restrict__ wSel,
    int* __restrict__ cnt, int* __restrict__ listTok, float* __restrict__ listW)
{
  __shared__ int lcnt[NE];
  __shared__ int base[NE];
  const int tid = threadIdx.x;
  if (tid < NE) lcnt[tid] = 0;
  __syncthreads();

  const int t = blockIdx.x * 256 + tid;
  const int e0 = eSel[t * 2 + 0];
  const int e1 = eSel[t * 2 + 1];
  const float w0 = wSel[t * 2 + 0];
  const float w1 = wSel[t * 2 + 1];
  const int l0 = atomicAdd(&lcnt[e0], 1);
  const int l1 = atomicAdd(&lcnt[e1], 1);
  __syncthreads();
  if (tid < NE) base[tid] = atomicAdd(&cnt[tid], lcnt[tid]);
  __syncthreads();

  const int p0 = base[e0] + l0;
  listTok[e0 * TOK + p0] = t * 2 + 0;   // token*2 + slot
  listW [e0 * TOK + p0] = w0;
  const int p1 = base[e1] + l1;
  listTok[e1 * TOK + p1] = t * 2 + 1;
  listW [e1 * TOK + p1] = w1;
}

// ---------------------------------------------------------------------------
// R12 moe_gemm: 256(tokens) x 256(f) tile, 4 waves, WAVE-TILE 128x128
// (8x8 16x16 fragments), BK=32, ring-2, asm ds_read (R11-proven).
//
// Post-mortem R11 (65us, MfmaUtil 21.5%): wall/block-iter 2167cy = LDS phase
// (read 576 + DMA-write 192, x2 blocks = 1540) + MFMA (516) SERIALIZED, and
// LDS traffic >= MFMA demand at the 128x64 wave-tile's 42.7 FLOP/LDS-byte.
// Fixes: (1) 128x128 wave-tile -> 64 FLOP/B: per-CU MFMA 2066cy > LDS
// ~1540cy (compute-bound at last); (2) read<->MFMA overlap: issue all 16
// ds_reads (af[4..7] LAST), lgkmcnt(4), MFMA mt0-3 cluster (hides last 4
// reads), lgkmcnt(0), MFMA mt4-7 (sched_barrier(0) fences, rule #18);
// (3) ring-2 (66KB -> still 2 blocks/CU): end-of-iter vmcnt(0) is a ~free
// drain since the 8 staging loads get the whole ~1000cy CMP to land.
// Swizzle identical to R11 (measured 0 conflicts): slot q of row r holds
// global quarter q^((r>>1)&3); write side (l&3)^((l>>3)&3); read side
// qg^((mrow>>1)&3).
// ---------------------------------------------------------------------------
#define WAITVM(n) asm volatile("s_waitcnt vmcnt(" #n ")" ::: "memory")

#define STG(kt, bs)                                                          \
  { const int off_ = (kt) * 32;                                              \
    gl_lds16(srcA0 + off_, &As[bs][w * 2048 + 0]);                           \
    gl_lds16(srcA1 + off_, &As[bs][w * 2048 + 512]);                         \
    gl_lds16(srcA2 + off_, &As[bs][w * 2048 + 1024]);                        \
    gl_lds16(srcA3 + off_, &As[bs][w * 2048 + 1536]);                        \
    gl_lds16(srcB0 + off_, &Bs[bs][w * 2048 + 0]);                           \
    gl_lds16(srcB1 + off_, &Bs[bs][w * 2048 + 512]);                         \
    gl_lds16(srcB2 + off_, &Bs[bs][w * 2048 + 1024]);                        \
    gl_lds16(srcB3 + off_, &Bs[bs][w * 2048 + 1536]); }

// A/B buffer stride 16384 B; mt/nt fragment step = 16 rows x 64 B = 1024 B
#define CMP(bs)                                                              \
  { const unsigned aA = asOff + (unsigned)(bs) * 16384u + rdA2;              \
    const unsigned bA = bsOff + (unsigned)(bs) * 16384u + rdB2;              \
    bf16x8 a0,a1,a2,a3,a4,a5,a6,a7,b0,b1,b2,b3,b4,b5,b6,b7;                  \
    asm volatile(                                                            \
      "ds_read_b128 %0, %16 offset:0\n\t"                                    \
      "ds_read_b128 %1, %16 offset:1024\n\t"                                 \
      "ds_read_b128 %2, %16 offset:2048\n\t"                                 \
      "ds_read_b128 %3, %16 offset:3072\n\t"                                 \
      "ds_read_b128 %8, %17 offset:0\n\t"                                    \
      "ds_read_b128 %9, %17 offset:1024\n\t"                                 \
      "ds_read_b128 %10, %17 offset:2048\n\t"                                \
      "ds_read_b128 %11, %17 offset:3072\n\t"                                \
      "ds_read_b128 %12, %17 offset:4096\n\t"                                \
      "ds_read_b128 %13, %17 offset:5120\n\t"                                \
      "ds_read_b128 %14, %17 offset:6144\n\t"                                \
      "ds_read_b128 %15, %17 offset:7168\n\t"                                \
      "ds_read_b128 %4, %16 offset:4096\n\t"                                 \
      "ds_read_b128 %5, %16 offset:5120\n\t"                                 \
      "ds_read_b128 %6, %16 offset:6144\n\t"                                 \
      "ds_read_b128 %7, %16 offset:7168\n\t"                                 \
      "s_waitcnt lgkmcnt(4)"                                                 \
      : "=&v"(a0),"=&v"(a1),"=&v"(a2),"=&v"(a3),                             \
        "=&v"(a4),"=&v"(a5),"=&v"(a6),"=&v"(a7),                             \
        "=&v"(b0),"=&v"(b1),"=&v"(b2),"=&v"(b3),                             \
        "=&v"(b4),"=&v"(b5),"=&v"(b6),"=&v"(b7)                              \
      : "v"(aA), "v"(bA)                                                     \
      : "memory");                                                           \
    __builtin_amdgcn_sched_barrier(0);                                       \
    bf16x8 afL[4] = {a0, a1, a2, a3};                                        \
    bf16x8 afH[4] = {a4, a5, a6, a7};                                        \
    bf16x8 bfr[8] = {b0, b1, b2, b3, b4, b5, b6, b7};                        \
    __builtin_amdgcn_s_setprio(1);                                           \
    _Pragma("unroll")                                                        \
    for (int mt = 0; mt < 4; ++mt)                                           \
      _Pragma("unroll")                                                      \
      for (int nt = 0; nt < 8; ++nt)                                         \
        acc[mt][nt] = __builtin_amdgcn_mfma_f32_16x16x32_bf16(               \
            afL[mt], bfr[nt], acc[mt][nt], 0, 0, 0);                         \
    __builtin_amdgcn_s_setprio(0);                                           \
    asm volatile("s_waitcnt lgkmcnt(0)" ::: "memory");                       \
    __builtin_amdgcn_sched_barrier(0);                                       \
    __builtin_amdgcn_s_setprio(1);                                           \
    _Pragma("unroll")                                                        \
    for (int mt = 0; mt < 4; ++mt)                                           \
      _Pragma("unroll")                                                      \
      for (int nt = 0; nt < 8; ++nt)                                         \
        acc[mt + 4][nt] = __builtin_amdgcn_mfma_f32_16x16x32_bf16(           \
            afH[mt], bfr[nt], acc[mt + 4][nt], 0, 0, 0);                     \
    __builtin_amdgcn_s_setprio(0); }

__global__ __launch_bounds__(256, 2) void moe_gemm(
    const unsigned short* __restrict__ xb, const unsigned short* __restrict__ Wt,
    const float* __restrict__ eb, const int* __restrict__ cnt,
    const int* __restrict__ listTok, const float* __restrict__ listW,
    __half* __restrict__ yslot)
{
  const int dId = blockIdx.x % NT;   // dId-major; NT%8==0 -> cT siblings share XCD
  const int cT  = blockIdx.x / NT;
  int e = -1, r0 = 0, rows = 0, accT = 0;
#pragma unroll
  for (int ee = 0; ee < NE; ++ee) {
    const int c = cnt[ee];
    const int nt = (c + 255) >> 8;
    if (dId >= accT && dId < accT + nt) {
      e = ee; r0 = (dId - accT) * 256;
      rows = c - r0; if (rows > 256) rows = 256;
    }
    accT += nt;
  }
  if (e < 0) return;   // block-uniform exit, before any barrier

  // ring-2: A 2x16KB + B 2x16KB + lists 2KB = 66KB -> 2 blocks/CU
  __shared__ __align__(16) unsigned short As[2][256 * 32];
  __shared__ __align__(16) unsigned short Bs[2][256 * 32];
  __shared__ int   tid_s[256];
  __shared__ float w_s[256];

  const int tid = threadIdx.x;
  if (tid < rows) {
    tid_s[tid] = listTok[e * TOK + r0 + tid];
    w_s[tid]   = listW [e * TOK + r0 + tid];
  } else {
    tid_s[tid] = 0;     // safe dummy row (token 0) — never stored
    w_s[tid]   = 0.0f;
  }
  __syncthreads();      // drains vmcnt -> counted region starts clean

  const int w    = tid >> 6;           // wave 0..3
  const int lane = tid & 63;
  // Staging: wave w owns A rows w*64..+63 and B rows w*64..+63 (4 calls each,
  // 16 rows/call). Lane l covers row r0c+(l>>2), slot l&3; pre-swizzled
  // global quarter = (l&3)^((l>>3)&3).
  const int qsrc = (lane & 3) ^ ((lane >> 3) & 3);
  const int lr   = lane >> 2;
  const unsigned short* srcA0 = xb + (size_t)(tid_s[w * 64 +  0 + lr] >> 1) * DIM + qsrc * 8;
  const unsigned short* srcA1 = xb + (size_t)(tid_s[w * 64 + 16 + lr] >> 1) * DIM + qsrc * 8;
  const unsigned short* srcA2 = xb + (size_t)(tid_s[w * 64 + 32 + lr] >> 1) * DIM + qsrc * 8;
  const unsigned short* srcA3 = xb + (size_t)(tid_s[w * 64 + 48 + lr] >> 1) * DIM + qsrc * 8;
  const size_t bbase = ((size_t)e * DIM + cT * 256 + w * 64) * DIM;
  const unsigned short* srcB0 = Wt + bbase + (size_t)( 0 + lr) * DIM + qsrc * 8;
  const unsigned short* srcB1 = Wt + bbase + (size_t)(16 + lr) * DIM + qsrc * 8;
  const unsigned short* srcB2 = Wt + bbase + (size_t)(32 + lr) * DIM + qsrc * 8;
  const unsigned short* srcB3 = Wt + bbase + (size_t)(48 + lr) * DIM + qsrc * 8;

  const int wr = w >> 1, wc = w & 1;   // 2x2 wave grid, 128x128 out each
  const int mrow = lane & 15;
  const int qg   = lane >> 4;
  const int s8   = (qg ^ ((mrow >> 1) & 3)) * 8;   // verified conflict-free
  const unsigned rdA2 = (unsigned)(((wr * 128 + mrow) * 32 + s8) * 2);  // bytes
  const unsigned rdB2 = (unsigned)(((wc * 128 + mrow) * 32 + s8) * 2);  // bytes
  const unsigned asOff = lds_off(&As[0][0]);
  const unsigned bsOff = lds_off(&Bs[0][0]);

  f32x4 acc[8][8];
#pragma unroll
  for (int i = 0; i < 8; ++i)
#pragma unroll
    for (int j = 0; j < 8; ++j)
      acc[i][j] = {0.f, 0.f, 0.f, 0.f};

  // prologue: tile 0 -> buf 0 (8 calls); short drain + barrier
  STG(0, 0);
  WAITVM(0);
  __builtin_amdgcn_s_barrier();

  int buf = 0;
#pragma unroll 1
  for (int kt = 0; kt < 32; ++kt) {
    if (kt < 31) STG(kt + 1, buf ^ 1);   // issue next tile's DMA first
    CMP(buf);                            // reads overlap MFMA (lgkm-counted)
    if (kt < 31) {
      WAITVM(0);                         // ~free: loads had whole CMP to land
      __builtin_amdgcn_s_barrier();
      buf ^= 1;
    }
  }

  // epilogue: C/D map col=lane&15, row=(lane>>4)*4+r
  const int colBase = cT * 256 + wc * 128 + mrow;
  float bias[8];
#pragma unroll
  for (int nt = 0; nt < 8; ++nt)
    bias[nt] = eb[(size_t)e * DIM + colBase + nt * 16];
#pragma unroll
  for (int mt = 0; mt < 8; ++mt) {
#pragma unroll
    for (int r = 0; r < 4; ++r) {
      const int rloc = wr * 128 + mt * 16 + (lane >> 4) * 4 + r;
      if (rloc < rows) {
        const int tk    = tid_s[rloc];
        const float wgt = w_s[rloc];
        __half* dst = yslot + ((size_t)(tk & 1) * TOK + (size_t)(tk >> 1)) * DIM;
#pragma unroll
        for (int nt = 0; nt < 8; ++nt)
          dst[colBase + nt * 16] = __float2half(wgt * (acc[mt][nt][r] + bias[nt]));
      }
    }
  }
}

__global__ __launch_bounds__(256) void combine(
    const __half* __restrict__ y0, const __half* __restrict__ y1,
    float4* __restrict__ out)
{
  const size_t i = (size_t)blockIdx.x * 256 + threadIdx.x;  // float4 index
  const ushort4 ua = ((const ushort4*)y0)[i];
  const ushort4 ub = ((const ushort4*)y1)[i];
  const __half* ah = (const __half*)&ua;
  const __half* bh = (const __half*)&ub;
  float4 o;
  o.x = __half2float(ah[0]) + __half2float(bh[0]);
  o.y = __half2float(ah[1]) + __half2float(bh[1]);
  o.z = __half2float(ah[2]) + __half2float(bh[2]);
  o.w = __half2float(ah[3]) + __half2float(bh[3]);
  out[i] = o;
}

extern "C" void kernel_launch(void* const* d_in, const int* in_sizes, int n_in,
                              void* d_out, int out_size, void* d_ws, size_t ws_size,
                              hipStream_t stream)
{
  const float* x  = (const float*)d_in[0];
  const float* gW = (const float*)d_in[1];
  const float* gb = (const float*)d_in[2];
  const float* eW = (const float*)d_in[3];
  const float* eb = (const float*)d_in[4];
  float* out = (float*)d_out;

  char* p = (char*)d_ws;
  unsigned short* xb = (unsigned short*)p;  p += (size_t)TOK * DIM * 2;       // 16 MB
  unsigned short* Wt = (unsigned short*)p;  p += (size_t)NE * DIM * DIM * 2;  // 16 MB
  __half* yslot = (__half*)p;               p += (size_t)2 * TOK * DIM * 2;   // 32 MB
  int* cnt = (int*)p;                       p += 256;
  int* listTok = (int*)p;                   p += (size_t)NE * TOK * 4;
  float* listW = (float*)p;                 p += (size_t)NE * TOK * 4;

  // eSel/wSel alias the head of yslot: consumed by scatter_kernel BEFORE
  // moe_gemm overwrites yslot (stream-ordered).
  int*   eSel = (int*)yslot;                        // TOK*2 ints = 64 KB
  float* wSel = (float*)((char*)yslot + TOK * 8);   // TOK*2 floats = 64 KB

  gate_transpose<<<4096, 256, 0, stream>>>(x, gW, gb, xb, eSel, wSel, cnt, eW, Wt);
  scatter_kernel<<<TOK / 256, 256, 0, stream>>>(eSel, wSel, cnt, listTok, listW);
  moe_gemm<<<NT * NCT, 256, 0, stream>>>(xb, Wt, eb, cnt, listTok, listW, yslot);
  combine<<<TOK * DIM / 4 / 256, 256, 0, stream>>>(
      yslot, yslot + (size_t)TOK * DIM, (float4*)out);
}

// Round 7
// 293.347 us; speedup vs baseline: 1.6475x; 1.6475x over previous
//
#include <hip/hip_runtime.h>
#include <hip/hip_fp16.h>
#include <stdint.h>

#define TOK 8192      // B*S
#define DIM 1024
#define NE 8
#define NT 72         // max 256-row tiles: 64 full + <=7 ragged (+1 safety)
#define NCT 4         // 1024 / 256 col-tiles

typedef short bf16x8 __attribute__((ext_vector_type(8)));
typedef float f32x4 __attribute__((ext_vector_type(4)));

__device__ __forceinline__ unsigned short f2bf(float f) {
  unsigned int u = __float_as_uint(f);
  u += 0x7FFFu + ((u >> 16) & 1u);
  return (unsigned short)(u >> 16);
}

__device__ __forceinline__ void gl_lds16(const void* g, void* l) {
  __builtin_amdgcn_global_load_lds(
      (__attribute__((address_space(1))) unsigned int*)(g),
      (__attribute__((address_space(3))) unsigned int*)(l), 16, 0, 0);
}

__device__ __forceinline__ unsigned lds_off(const void* p) {
  // generic -> LDS(AS3) pointer -> 32-bit LDS byte offset
  return (unsigned)(size_t)(__attribute__((address_space(3))) const void*)p;
}

// gate and transpose_w fused into one dispatch (blockIdx-uniform branch,
// 32KB LDS union). Blocks 0..2047: gate; 2048..4095: W transpose.
__global__ __launch_bounds__(256) void gate_transpose(
    const float* __restrict__ x, const float* __restrict__ gW,
    const float* __restrict__ gb, unsigned short* __restrict__ xb,
    int* __restrict__ eSel, float* __restrict__ wSel, int* __restrict__ cnt,
    const float* __restrict__ W, unsigned short* __restrict__ Wt)
{
  __shared__ __align__(16) float smem[NE * DIM];   // 32 KB union

  if (blockIdx.x >= 2048) {
    // ---- transpose_w branch: expert_W [e][d][f] fp32 -> Wt [e][f][d] bf16
    float (*t2)[65] = (float(*)[65])smem;          // 64 x 65 padded
    const int b  = blockIdx.x - 2048;
    const int e  = b >> 8;                 // 256 tiles per expert
    const int db = (b >> 4) & 15;          // d (k) block
    const int fb = b & 15;                 // f block
    const int d0 = db * 64, f0 = fb * 64;
    const int tid = threadIdx.x;
#pragma unroll
    for (int h = 0; h < 4; ++h) {
      const int idx = tid + h * 256;
      const int r = idx >> 4, c4 = idx & 15;
      float4 v = *(const float4*)&W[((size_t)e * DIM + d0 + r) * DIM + f0 + c4 * 4];
      t2[r][c4 * 4 + 0] = v.x;
      t2[r][c4 * 4 + 1] = v.y;
      t2[r][c4 * 4 + 2] = v.z;
      t2[r][c4 * 4 + 3] = v.w;
    }
    __syncthreads();
#pragma unroll
    for (int h = 0; h < 8; ++h) {
      const int o = tid + h * 256;
      const int f = o >> 5, k2 = (o & 31) * 2;
      const unsigned int lo = f2bf(t2[k2][f]);
      const unsigned int hi = f2bf(t2[k2 + 1][f]);
      *(unsigned int*)&Wt[((size_t)e * DIM + f0 + f) * DIM + d0 + k2] =
          lo | (hi << 16);
    }
    return;
  }

  // ---- gate branch: x row -> bf16 + gating dots (fp64 acc) + top-2 picks
  if (blockIdx.x == 0 && threadIdx.x < NE) cnt[threadIdx.x] = 0;

  float* gWs = smem;                // [e][d], 32 KB
#pragma unroll
  for (int h = 0; h < 8; ++h) {
    const int m = threadIdx.x + h * 256;       // float4 id over gW (2048)
    float4 v = ((const float4*)gW)[m];
    const int d = m >> 1, e0 = (m & 1) * 4;    // gW is [d][e]
    gWs[(e0 + 0) * DIM + d] = v.x;
    gWs[(e0 + 1) * DIM + d] = v.y;
    gWs[(e0 + 2) * DIM + d] = v.z;
    gWs[(e0 + 3) * DIM + d] = v.w;
  }
  __syncthreads();

  const int wave = threadIdx.x >> 6;
  const int lane = threadIdx.x & 63;
  const int t = blockIdx.x * 4 + wave;
  const float4* xrow = (const float4*)(x + (size_t)t * DIM);
  ushort4* xbrow = (ushort4*)(xb + (size_t)t * DIM);

  double acc[NE];
#pragma unroll
  for (int e = 0; e < NE; ++e) acc[e] = 0.0;

#pragma unroll
  for (int i = 0; i < 4; ++i) {
    const int j = i * 64 + lane;         // float4 index within row (0..255)
    float4 v = xrow[j];
    ushort4 pk;
    pk.x = f2bf(v.x); pk.y = f2bf(v.y); pk.z = f2bf(v.z); pk.w = f2bf(v.w);
    xbrow[j] = pk;
#pragma unroll
    for (int e = 0; e < NE; ++e) {
      float4 gv = *(const float4*)&gWs[e * DIM + j * 4];
      acc[e] += (double)v.x * (double)gv.x + (double)v.y * (double)gv.y
              + (double)v.z * (double)gv.z + (double)v.w * (double)gv.w;
    }
  }
#pragma unroll
  for (int off = 32; off > 0; off >>= 1) {
#pragma unroll
    for (int e = 0; e < NE; ++e)
      acc[e] += __shfl_xor(acc[e], off, 64);
  }

  if (lane == 0) {
    double s[NE];
#pragma unroll
    for (int e = 0; e < NE; ++e) {
      s[e] = acc[e] + (double)gb[e];
      if (s[e] < 1e-4) s[e] = 1e-4;     // clamp-min(EPS), TEMP=1
    }
    int e0 = 0;
    for (int e = 1; e < NE; ++e) if (s[e] > s[e0]) e0 = e;
    int e1 = (e0 == 0) ? 1 : 0;
    for (int e = 0; e < NE; ++e) if (e != e0 && s[e] > s[e1]) e1 = e;
    float m = (float)s[e0];
    float Z = 0.f, pf[NE];
#pragma unroll
    for (int e = 0; e < NE; ++e) { pf[e] = __expf((float)s[e] - m); Z += pf[e]; }
    float w0 = pf[e0] / Z; if (w0 < 0.1f) w0 = 0.1f;
    float w1 = pf[e1] / Z; if (w1 < 0.1f) w1 = 0.1f;
    const float inv = 0.5f / (w0 + w1);   // /total /K
    eSel[t * 2 + 0] = e0;
    eSel[t * 2 + 1] = e1;
    wSel[t * 2 + 0] = w0 * inv;
    wSel[t * 2 + 1] = w1 * inv;
  }
}

// Two-level scatter: LDS histogram per block, 8 global atomics per block.
__global__ __launch_bounds__(256) void scatter_kernel(
    const int* __restrict__ eSel, const float* __restrict__ wSel,
    int* __restrict__ cnt, int* __restrict__ listTok, float* __restrict__ listW)
{
  __shared__ int lcnt[NE];
  __shared__ int base[NE];
  const int tid = threadIdx.x;
  if (tid < NE) lcnt[tid] = 0;
  __syncthreads();

  const int t = blockIdx.x * 256 + tid;
  const int e0 = eSel[t * 2 + 0];
  const int e1 = eSel[t * 2 + 1];
  const float w0 = wSel[t * 2 + 0];
  const float w1 = wSel[t * 2 + 1];
  const int l0 = atomicAdd(&lcnt[e0], 1);
  const int l1 = atomicAdd(&lcnt[e1], 1);
  __syncthreads();
  if (tid < NE) base[tid] = atomicAdd(&cnt[tid], lcnt[tid]);
  __syncthreads();

  const int p0 = base[e0] + l0;
  listTok[e0 * TOK + p0] = t * 2 + 0;   // token*2 + slot
  listW [e0 * TOK + p0] = w0;
  const int p1 = base[e1] + l1;
  listTok[e1 * TOK + p1] = t * 2 + 1;
  listW [e1 * TOK + p1] = w1;
}

// ---------------------------------------------------------------------------
// R13 moe_gemm: R12 VERBATIM except __launch_bounds__(256, 1).
//
// Post-mortem R12 (355us, WRITE_SIZE 610MB, VGPR 128, MfmaUtil 0.3-4%):
// launch_bounds(256,2) caps 256 VGPR/wave; acc[8][8]=256 f32 alone hits the
// cap -> whole accumulator spilled to scratch (the 578MB extra HBM writes).
// The geometry itself PASSED refcheck. Occupancy ladder (m69): >256 regs
// requires 1 wave/SIMD -> declare (256,1): ~380 regs fit in the 512 budget,
// no spill. At 1 wave/SIMD: 4 waves/CU, 1 block/CU; the MFMA pipe is kept
// busy by the 64-MFMA clusters (1242 cy/iter vs LDS ~770-1130 cy/iter ->
// first genuinely compute-bound config); DMA prefetch (counted vmcnt) and
// the split lgkmcnt(4)/(0) read<->MFMA overlap hide most of the rest.
// Swizzle / ring-2 / asm ds_read identical to R12 (0 conflicts measured).
// ---------------------------------------------------------------------------
#define WAITVM(n) asm volatile("s_waitcnt vmcnt(" #n ")" ::: "memory")

#define STG(kt, bs)                                                          \
  { const int off_ = (kt) * 32;                                              \
    gl_lds16(srcA0 + off_, &As[bs][w * 2048 + 0]);                           \
    gl_lds16(srcA1 + off_, &As[bs][w * 2048 + 512]);                         \
    gl_lds16(srcA2 + off_, &As[bs][w * 2048 + 1024]);                        \
    gl_lds16(srcA3 + off_, &As[bs][w * 2048 + 1536]);                        \
    gl_lds16(srcB0 + off_, &Bs[bs][w * 2048 + 0]);                           \
    gl_lds16(srcB1 + off_, &Bs[bs][w * 2048 + 512]);                         \
    gl_lds16(srcB2 + off_, &Bs[bs][w * 2048 + 1024]);                        \
    gl_lds16(srcB3 + off_, &Bs[bs][w * 2048 + 1536]); }

// A/B buffer stride 16384 B; mt/nt fragment step = 16 rows x 64 B = 1024 B
#define CMP(bs)                                                              \
  { const unsigned aA = asOff + (unsigned)(bs) * 16384u + rdA2;              \
    const unsigned bA = bsOff + (unsigned)(bs) * 16384u + rdB2;              \
    bf16x8 a0,a1,a2,a3,a4,a5,a6,a7,b0,b1,b2,b3,b4,b5,b6,b7;                  \
    asm volatile(                                                            \
      "ds_read_b128 %0, %16 offset:0\n\t"                                    \
      "ds_read_b128 %1, %16 offset:1024\n\t"                                 \
      "ds_read_b128 %2, %16 offset:2048\n\t"                                 \
      "ds_read_b128 %3, %16 offset:3072\n\t"                                 \
      "ds_read_b128 %8, %17 offset:0\n\t"                                    \
      "ds_read_b128 %9, %17 offset:1024\n\t"                                 \
      "ds_read_b128 %10, %17 offset:2048\n\t"                                \
      "ds_read_b128 %11, %17 offset:3072\n\t"                                \
      "ds_read_b128 %12, %17 offset:4096\n\t"                                \
      "ds_read_b128 %13, %17 offset:5120\n\t"                                \
      "ds_read_b128 %14, %17 offset:6144\n\t"                                \
      "ds_read_b128 %15, %17 offset:7168\n\t"                                \
      "ds_read_b128 %4, %16 offset:4096\n\t"                                 \
      "ds_read_b128 %5, %16 offset:5120\n\t"                                 \
      "ds_read_b128 %6, %16 offset:6144\n\t"                                 \
      "ds_read_b128 %7, %16 offset:7168\n\t"                                 \
      "s_waitcnt lgkmcnt(4)"                                                 \
      : "=&v"(a0),"=&v"(a1),"=&v"(a2),"=&v"(a3),                             \
        "=&v"(a4),"=&v"(a5),"=&v"(a6),"=&v"(a7),                             \
        "=&v"(b0),"=&v"(b1),"=&v"(b2),"=&v"(b3),                             \
        "=&v"(b4),"=&v"(b5),"=&v"(b6),"=&v"(b7)                              \
      : "v"(aA), "v"(bA)                                                     \
      : "memory");                                                           \
    __builtin_amdgcn_sched_barrier(0);                                       \
    bf16x8 afL[4] = {a0, a1, a2, a3};                                        \
    bf16x8 afH[4] = {a4, a5, a6, a7};                                        \
    bf16x8 bfr[8] = {b0, b1, b2, b3, b4, b5, b6, b7};                        \
    __builtin_amdgcn_s_setprio(1);                                           \
    _Pragma("unroll")                                                        \
    for (int mt = 0; mt < 4; ++mt)                                           \
      _Pragma("unroll")                                                      \
      for (int nt = 0; nt < 8; ++nt)                                         \
        acc[mt][nt] = __builtin_amdgcn_mfma_f32_16x16x32_bf16(               \
            afL[mt], bfr[nt], acc[mt][nt], 0, 0, 0);                         \
    __builtin_amdgcn_s_setprio(0);                                           \
    asm volatile("s_waitcnt lgkmcnt(0)" ::: "memory");                       \
    __builtin_amdgcn_sched_barrier(0);                                       \
    __builtin_amdgcn_s_setprio(1);                                           \
    _Pragma("unroll")                                                        \
    for (int mt = 0; mt < 4; ++mt)                                           \
      _Pragma("unroll")                                                      \
      for (int nt = 0; nt < 8; ++nt)                                         \
        acc[mt + 4][nt] = __builtin_amdgcn_mfma_f32_16x16x32_bf16(           \
            afH[mt], bfr[nt], acc[mt + 4][nt], 0, 0, 0);                     \
    __builtin_amdgcn_s_setprio(0); }

__global__ __launch_bounds__(256, 1) void moe_gemm(
    const unsigned short* __restrict__ xb, const unsigned short* __restrict__ Wt,
    const float* __restrict__ eb, const int* __restrict__ cnt,
    const int* __restrict__ listTok, const float* __restrict__ listW,
    __half* __restrict__ yslot)
{
  const int dId = blockIdx.x % NT;   // dId-major; NT%8==0 -> cT siblings share XCD
  const int cT  = blockIdx.x / NT;
  int e = -1, r0 = 0, rows = 0, accT = 0;
#pragma unroll
  for (int ee = 0; ee < NE; ++ee) {
    const int c = cnt[ee];
    const int nt = (c + 255) >> 8;
    if (dId >= accT && dId < accT + nt) {
      e = ee; r0 = (dId - accT) * 256;
      rows = c - r0; if (rows > 256) rows = 256;
    }
    accT += nt;
  }
  if (e < 0) return;   // block-uniform exit, before any barrier

  // ring-2: A 2x16KB + B 2x16KB + lists 2KB = 66KB
  __shared__ __align__(16) unsigned short As[2][256 * 32];
  __shared__ __align__(16) unsigned short Bs[2][256 * 32];
  __shared__ int   tid_s[256];
  __shared__ float w_s[256];

  const int tid = threadIdx.x;
  if (tid < rows) {
    tid_s[tid] = listTok[e * TOK + r0 + tid];
    w_s[tid]   = listW [e * TOK + r0 + tid];
  } else {
    tid_s[tid] = 0;     // safe dummy row (token 0) — never stored
    w_s[tid]   = 0.0f;
  }
  __syncthreads();      // drains vmcnt -> counted region starts clean

  const int w    = tid >> 6;           // wave 0..3
  const int lane = tid & 63;
  // Staging: wave w owns A rows w*64..+63 and B rows w*64..+63 (4 calls each,
  // 16 rows/call). Lane l covers row r0c+(l>>2), slot l&3; pre-swizzled
  // global quarter = (l&3)^((l>>3)&3).
  const int qsrc = (lane & 3) ^ ((lane >> 3) & 3);
  const int lr   = lane >> 2;
  const unsigned short* srcA0 = xb + (size_t)(tid_s[w * 64 +  0 + lr] >> 1) * DIM + qsrc * 8;
  const unsigned short* srcA1 = xb + (size_t)(tid_s[w * 64 + 16 + lr] >> 1) * DIM + qsrc * 8;
  const unsigned short* srcA2 = xb + (size_t)(tid_s[w * 64 + 32 + lr] >> 1) * DIM + qsrc * 8;
  const unsigned short* srcA3 = xb + (size_t)(tid_s[w * 64 + 48 + lr] >> 1) * DIM + qsrc * 8;
  const size_t bbase = ((size_t)e * DIM + cT * 256 + w * 64) * DIM;
  const unsigned short* srcB0 = Wt + bbase + (size_t)( 0 + lr) * DIM + qsrc * 8;
  const unsigned short* srcB1 = Wt + bbase + (size_t)(16 + lr) * DIM + qsrc * 8;
  const unsigned short* srcB2 = Wt + bbase + (size_t)(32 + lr) * DIM + qsrc * 8;
  const unsigned short* srcB3 = Wt + bbase + (size_t)(48 + lr) * DIM + qsrc * 8;

  const int wr = w >> 1, wc = w & 1;   // 2x2 wave grid, 128x128 out each
  const int mrow = lane & 15;
  const int qg   = lane >> 4;
  const int s8   = (qg ^ ((mrow >> 1) & 3)) * 8;   // verified conflict-free
  const unsigned rdA2 = (unsigned)(((wr * 128 + mrow) * 32 + s8) * 2);  // bytes
  const unsigned rdB2 = (unsigned)(((wc * 128 + mrow) * 32 + s8) * 2);  // bytes
  const unsigned asOff = lds_off(&As[0][0]);
  const unsigned bsOff = lds_off(&Bs[0][0]);

  f32x4 acc[8][8];
#pragma unroll
  for (int i = 0; i < 8; ++i)
#pragma unroll
    for (int j = 0; j < 8; ++j)
      acc[i][j] = {0.f, 0.f, 0.f, 0.f};

  // prologue: tile 0 -> buf 0 (8 calls); short drain + barrier
  STG(0, 0);
  WAITVM(0);
  __builtin_amdgcn_s_barrier();

  int buf = 0;
#pragma unroll 1
  for (int kt = 0; kt < 32; ++kt) {
    if (kt < 31) STG(kt + 1, buf ^ 1);   // issue next tile's DMA first
    CMP(buf);                            // reads overlap MFMA (lgkm-counted)
    if (kt < 31) {
      WAITVM(0);                         // ~free: loads had whole CMP to land
      __builtin_amdgcn_s_barrier();
      buf ^= 1;
    }
  }

  // epilogue: C/D map col=lane&15, row=(lane>>4)*4+r
  const int colBase = cT * 256 + wc * 128 + mrow;
  float bias[8];
#pragma unroll
  for (int nt = 0; nt < 8; ++nt)
    bias[nt] = eb[(size_t)e * DIM + colBase + nt * 16];
#pragma unroll
  for (int mt = 0; mt < 8; ++mt) {
#pragma unroll
    for (int r = 0; r < 4; ++r) {
      const int rloc = wr * 128 + mt * 16 + (lane >> 4) * 4 + r;
      if (rloc < rows) {
        const int tk    = tid_s[rloc];
        const float wgt = w_s[rloc];
        __half* dst = yslot + ((size_t)(tk & 1) * TOK + (size_t)(tk >> 1)) * DIM;
#pragma unroll
        for (int nt = 0; nt < 8; ++nt)
          dst[colBase + nt * 16] = __float2half(wgt * (acc[mt][nt][r] + bias[nt]));
      }
    }
  }
}

__global__ __launch_bounds__(256) void combine(
    const __half* __restrict__ y0, const __half* __restrict__ y1,
    float4* __restrict__ out)
{
  const size_t i = (size_t)blockIdx.x * 256 + threadIdx.x;  // float4 index
  const ushort4 ua = ((const ushort4*)y0)[i];
  const ushort4 ub = ((const ushort4*)y1)[i];
  const __half* ah = (const __half*)&ua;
  const __half* bh = (const __half*)&ub;
  float4 o;
  o.x = __half2float(ah[0]) + __half2float(bh[0]);
  o.y = __half2float(ah[1]) + __half2float(bh[1]);
  o.z = __half2float(ah[2]) + __half2float(bh[2]);
  o.w = __half2float(ah[3]) + __half2float(bh[3]);
  out[i] = o;
}

extern "C" void kernel_launch(void* const* d_in, const int* in_sizes, int n_in,
                              void* d_out, int out_size, void* d_ws, size_t ws_size,
                              hipStream_t stream)
{
  const float* x  = (const float*)d_in[0];
  const float* gW = (const float*)d_in[1];
  const float* gb = (const float*)d_in[2];
  const float* eW = (const float*)d_in[3];
  const float* eb = (const float*)d_in[4];
  float* out = (float*)d_out;

  char* p = (char*)d_ws;
  unsigned short* xb = (unsigned short*)p;  p += (size_t)TOK * DIM * 2;       // 16 MB
  unsigned short* Wt = (unsigned short*)p;  p += (size_t)NE * DIM * DIM * 2;  // 16 MB
  __half* yslot = (__half*)p;               p += (size_t)2 * TOK * DIM * 2;   // 32 MB
  int* cnt = (int*)p;                       p += 256;
  int* listTok = (int*)p;                   p += (size_t)NE * TOK * 4;
  float* listW = (float*)p;                 p += (size_t)NE * TOK * 4;

  // eSel/wSel alias the head of yslot: consumed by scatter_kernel BEFORE
  // moe_gemm overwrites yslot (stream-ordered).
  int*   eSel = (int*)yslot;                        // TOK*2 ints = 64 KB
  float* wSel = (float*)((char*)yslot + TOK * 8);   // TOK*2 floats = 64 KB

  gate_transpose<<<4096, 256, 0, stream>>>(x, gW, gb, xb, eSel, wSel, cnt, eW, Wt);
  scatter_kernel<<<TOK / 256, 256, 0, stream>>>(eSel, wSel, cnt, listTok, listW);
  moe_gemm<<<NT * NCT, 256, 0, stream>>>(xb, Wt, eb, cnt, listTok, listW, yslot);
  combine<<<TOK * DIM / 4 / 256, 256, 0, stream>>>(
      yslot, yslot + (size_t)TOK * DIM, (float4*)out);
}

// Round 8
// 199.815 us; speedup vs baseline: 2.4187x; 1.4681x over previous
//
#include <hip/hip_runtime.h>
#include <hip/hip_fp16.h>
#include <stdint.h>

#define TOK 8192      // B*S
#define DIM 1024
#define NE 8
#define NT 72         // max 256-row tiles: 64 full + <=7 ragged (+1 safety)
#define NCT 4         // 1024 / 256 col-tiles

typedef short bf16x8 __attribute__((ext_vector_type(8)));
typedef float f32x4 __attribute__((ext_vector_type(4)));

__device__ __forceinline__ unsigned short f2bf(float f) {
  unsigned int u = __float_as_uint(f);
  u += 0x7FFFu + ((u >> 16) & 1u);
  return (unsigned short)(u >> 16);
}

__device__ __forceinline__ void gl_lds16(const void* g, void* l) {
  __builtin_amdgcn_global_load_lds(
      (__attribute__((address_space(1))) unsigned int*)(g),
      (__attribute__((address_space(3))) unsigned int*)(l), 16, 0, 0);
}

__device__ __forceinline__ unsigned lds_off(const void* p) {
  // generic -> LDS(AS3) pointer -> 32-bit LDS byte offset
  return (unsigned)(size_t)(__attribute__((address_space(3))) const void*)p;
}

// gate and transpose_w fused into one dispatch (blockIdx-uniform branch,
// 32KB LDS union). Blocks 0..2047: gate; 2048..4095: W transpose.
__global__ __launch_bounds__(256) void gate_transpose(
    const float* __restrict__ x, const float* __restrict__ gW,
    const float* __restrict__ gb, unsigned short* __restrict__ xb,
    int* __restrict__ eSel, float* __restrict__ wSel, int* __restrict__ cnt,
    const float* __restrict__ W, unsigned short* __restrict__ Wt)
{
  __shared__ __align__(16) float smem[NE * DIM];   // 32 KB union

  if (blockIdx.x >= 2048) {
    // ---- transpose_w branch: expert_W [e][d][f] fp32 -> Wt [e][f][d] bf16
    float (*t2)[65] = (float(*)[65])smem;          // 64 x 65 padded
    const int b  = blockIdx.x - 2048;
    const int e  = b >> 8;                 // 256 tiles per expert
    const int db = (b >> 4) & 15;          // d (k) block
    const int fb = b & 15;                 // f block
    const int d0 = db * 64, f0 = fb * 64;
    const int tid = threadIdx.x;
#pragma unroll
    for (int h = 0; h < 4; ++h) {
      const int idx = tid + h * 256;
      const int r = idx >> 4, c4 = idx & 15;
      float4 v = *(const float4*)&W[((size_t)e * DIM + d0 + r) * DIM + f0 + c4 * 4];
      t2[r][c4 * 4 + 0] = v.x;
      t2[r][c4 * 4 + 1] = v.y;
      t2[r][c4 * 4 + 2] = v.z;
      t2[r][c4 * 4 + 3] = v.w;
    }
    __syncthreads();
#pragma unroll
    for (int h = 0; h < 8; ++h) {
      const int o = tid + h * 256;
      const int f = o >> 5, k2 = (o & 31) * 2;
      const unsigned int lo = f2bf(t2[k2][f]);
      const unsigned int hi = f2bf(t2[k2 + 1][f]);
      *(unsigned int*)&Wt[((size_t)e * DIM + f0 + f) * DIM + d0 + k2] =
          lo | (hi << 16);
    }
    return;
  }

  // ---- gate branch: x row -> bf16 + gating dots (fp64 acc) + top-2 picks
  if (blockIdx.x == 0 && threadIdx.x < NE) cnt[threadIdx.x] = 0;

  float* gWs = smem;                // [e][d], 32 KB
#pragma unroll
  for (int h = 0; h < 8; ++h) {
    const int m = threadIdx.x + h * 256;       // float4 id over gW (2048)
    float4 v = ((const float4*)gW)[m];
    const int d = m >> 1, e0 = (m & 1) * 4;    // gW is [d][e]
    gWs[(e0 + 0) * DIM + d] = v.x;
    gWs[(e0 + 1) * DIM + d] = v.y;
    gWs[(e0 + 2) * DIM + d] = v.z;
    gWs[(e0 + 3) * DIM + d] = v.w;
  }
  __syncthreads();

  const int wave = threadIdx.x >> 6;
  const int lane = threadIdx.x & 63;
  const int t = blockIdx.x * 4 + wave;
  const float4* xrow = (const float4*)(x + (size_t)t * DIM);
  ushort4* xbrow = (ushort4*)(xb + (size_t)t * DIM);

  double acc[NE];
#pragma unroll
  for (int e = 0; e < NE; ++e) acc[e] = 0.0;

#pragma unroll
  for (int i = 0; i < 4; ++i) {
    const int j = i * 64 + lane;         // float4 index within row (0..255)
    float4 v = xrow[j];
    ushort4 pk;
    pk.x = f2bf(v.x); pk.y = f2bf(v.y); pk.z = f2bf(v.z); pk.w = f2bf(v.w);
    xbrow[j] = pk;
#pragma unroll
    for (int e = 0; e < NE; ++e) {
      float4 gv = *(const float4*)&gWs[e * DIM + j * 4];
      acc[e] += (double)v.x * (double)gv.x + (double)v.y * (double)gv.y
              + (double)v.z * (double)gv.z + (double)v.w * (double)gv.w;
    }
  }
#pragma unroll
  for (int off = 32; off > 0; off >>= 1) {
#pragma unroll
    for (int e = 0; e < NE; ++e)
      acc[e] += __shfl_xor(acc[e], off, 64);
  }

  if (lane == 0) {
    double s[NE];
#pragma unroll
    for (int e = 0; e < NE; ++e) {
      s[e] = acc[e] + (double)gb[e];
      if (s[e] < 1e-4) s[e] = 1e-4;     // clamp-min(EPS), TEMP=1
    }
    int e0 = 0;
    for (int e = 1; e < NE; ++e) if (s[e] > s[e0]) e0 = e;
    int e1 = (e0 == 0) ? 1 : 0;
    for (int e = 0; e < NE; ++e) if (e != e0 && s[e] > s[e1]) e1 = e;
    float m = (float)s[e0];
    float Z = 0.f, pf[NE];
#pragma unroll
    for (int e = 0; e < NE; ++e) { pf[e] = __expf((float)s[e] - m); Z += pf[e]; }
    float w0 = pf[e0] / Z; if (w0 < 0.1f) w0 = 0.1f;
    float w1 = pf[e1] / Z; if (w1 < 0.1f) w1 = 0.1f;
    const float inv = 0.5f / (w0 + w1);   // /total /K
    eSel[t * 2 + 0] = e0;
    eSel[t * 2 + 1] = e1;
    wSel[t * 2 + 0] = w0 * inv;
    wSel[t * 2 + 1] = w1 * inv;
  }
}

// Two-level scatter: LDS histogram per block, 8 global atomics per block.
__global__ __launch_bounds__(256) void scatter_kernel(
    const int* __restrict__ eSel, const float* __restrict__ wSel,
    int* __restrict__ cnt, int* __restrict__ listTok, float* __restrict__ listW)
{
  __shared__ int lcnt[NE];
  __shared__ int base[NE];
  const int tid = threadIdx.x;
  if (tid < NE) lcnt[tid] = 0;
  __syncthreads();

  const int t = blockIdx.x * 256 + tid;
  const int e0 = eSel[t * 2 + 0];
  const int e1 = eSel[t * 2 + 1];
  const float w0 = wSel[t * 2 + 0];
  const float w1 = wSel[t * 2 + 1];
  const int l0 = atomicAdd(&lcnt[e0], 1);
  const int l1 = atomicAdd(&lcnt[e1], 1);
  __syncthreads();
  if (tid < NE) base[tid] = atomicAdd(&cnt[tid], lcnt[tid]);
  __syncthreads();

  const int p0 = base[e0] + l0;
  listTok[e0 * TOK + p0] = t * 2 + 0;   // token*2 + slot
  listW [e0 * TOK + p0] = w0;
  const int p1 = base[e1] + l1;
  listTok[e1 * TOK + p1] = t * 2 + 1;
  listW [e1 * TOK + p1] = w1;
}

// ---------------------------------------------------------------------------
// R14 moe_gemm: 256(tokens) x 256(f) tile, 512 threads / 8 waves (2M x 4N),
// wave-tile 128x64 (acc[8][4] = 128 regs), BK=32, RING-3 LDS, counted
// vmcnt(4), asm ds_read with lgkm-split overlap.
//
// Post-mortems driving this:
//  - R13: 128x128 wave-tile = 256 acc regs -> register-infeasible (VGPR=256,
//    spill, 7% MfmaUtil). 128x64 is the feasible max (fits 2 waves/SIMD).
//  - R11 (best, 65us): its ring-2 ended EVERY iter with vmcnt(0), draining
//    the just-issued scattered A-gather DMA (~200-900cy latency) -> the
//    ~600cy/iter stall its counters showed. Ring-3 + end-of-iter vmcnt(4)
//    retires only tile t+1 and keeps tile t+2's 4 calls in flight: no vmem
//    drain in the main loop (m218's counted-vs-drain0 lever, done right).
//  - 1 block/CU of 8 barrier-synced waves (2/SIMD): wave stagger lets one
//    wave's MFMA cover another's ds_reads; DMA write traffic halves vs 2
//    independent 4-wave blocks.
// Swizzle (verified 0 conflicts, R10/R11): LDS slot q of row r holds global
// quarter q^((r>>1)&3); write side (l&3)^((l>>3)&3); read side
// qg^((mrow>>1)&3). Staging rows per call are 16-multiples so the write-side
// formula is exact.
// Ring-3 bookkeeping: iter kt stages tile kt+2 into slot (kt+2)%3 (that slot
// held tile kt-1, fully consumed before the barrier just crossed); end-of-
// iter vmcnt(4) retires tile kt+1 (4 calls), leaves kt+2 in flight; tail:
// vmcnt(0) at kt=30 only.
// ---------------------------------------------------------------------------
#define WAITVM(n) asm volatile("s_waitcnt vmcnt(" #n ")" ::: "memory")

#define STG(kt, bs)                                                          \
  { const int off_ = (kt) * 32;                                              \
    gl_lds16(srcA0 + off_, &As[bs][w * 512]);                                \
    gl_lds16(srcA1 + off_, &As[bs][128 * 32 + w * 512]);                     \
    gl_lds16(srcB0 + off_, &Bs[bs][w * 512]);                                \
    gl_lds16(srcB1 + off_, &Bs[bs][128 * 32 + w * 512]); }

// buffer stride 16384 B; fragment step = 16 rows x 64 B = 1024 B
#define CMP(bs)                                                              \
  { const unsigned aA = asOff + (unsigned)(bs) * 16384u + rdA2;              \
    const unsigned bA = bsOff + (unsigned)(bs) * 16384u + rdB2;              \
    bf16x8 a0,a1,a2,a3,a4,a5,a6,a7,b0,b1,b2,b3;                              \
    asm volatile(                                                            \
      "ds_read_b128 %0, %12 offset:0\n\t"                                    \
      "ds_read_b128 %1, %12 offset:1024\n\t"                                 \
      "ds_read_b128 %2, %12 offset:2048\n\t"                                 \
      "ds_read_b128 %3, %12 offset:3072\n\t"                                 \
      "ds_read_b128 %8, %13 offset:0\n\t"                                    \
      "ds_read_b128 %9, %13 offset:1024\n\t"                                 \
      "ds_read_b128 %10, %13 offset:2048\n\t"                                \
      "ds_read_b128 %11, %13 offset:3072\n\t"                                \
      "ds_read_b128 %4, %12 offset:4096\n\t"                                 \
      "ds_read_b128 %5, %12 offset:5120\n\t"                                 \
      "ds_read_b128 %6, %12 offset:6144\n\t"                                 \
      "ds_read_b128 %7, %12 offset:7168\n\t"                                 \
      "s_waitcnt lgkmcnt(4)"                                                 \
      : "=&v"(a0),"=&v"(a1),"=&v"(a2),"=&v"(a3),                             \
        "=&v"(a4),"=&v"(a5),"=&v"(a6),"=&v"(a7),                             \
        "=&v"(b0),"=&v"(b1),"=&v"(b2),"=&v"(b3)                              \
      : "v"(aA), "v"(bA)                                                     \
      : "memory");                                                           \
    __builtin_amdgcn_sched_barrier(0);                                       \
    bf16x8 afL[4] = {a0, a1, a2, a3};                                        \
    bf16x8 afH[4] = {a4, a5, a6, a7};                                        \
    bf16x8 bfr[4] = {b0, b1, b2, b3};                                        \
    __builtin_amdgcn_s_setprio(1);                                           \
    _Pragma("unroll")                                                        \
    for (int mt = 0; mt < 4; ++mt)                                           \
      _Pragma("unroll")                                                      \
      for (int nt = 0; nt < 4; ++nt)                                         \
        acc[mt][nt] = __builtin_amdgcn_mfma_f32_16x16x32_bf16(               \
            afL[mt], bfr[nt], acc[mt][nt], 0, 0, 0);                         \
    __builtin_amdgcn_s_setprio(0);                                           \
    asm volatile("s_waitcnt lgkmcnt(0)" ::: "memory");                       \
    __builtin_amdgcn_sched_barrier(0);                                       \
    __builtin_amdgcn_s_setprio(1);                                           \
    _Pragma("unroll")                                                        \
    for (int mt = 0; mt < 4; ++mt)                                           \
      _Pragma("unroll")                                                      \
      for (int nt = 0; nt < 4; ++nt)                                         \
        acc[mt + 4][nt] = __builtin_amdgcn_mfma_f32_16x16x32_bf16(           \
            afH[mt], bfr[nt], acc[mt + 4][nt], 0, 0, 0);                     \
    __builtin_amdgcn_s_setprio(0); }

__global__ __launch_bounds__(512, 2) void moe_gemm(
    const unsigned short* __restrict__ xb, const unsigned short* __restrict__ Wt,
    const float* __restrict__ eb, const int* __restrict__ cnt,
    const int* __restrict__ listTok, const float* __restrict__ listW,
    __half* __restrict__ yslot)
{
  const int dId = blockIdx.x % NT;   // dId-major; NT%8==0 -> cT siblings share XCD
  const int cT  = blockIdx.x / NT;
  int e = -1, r0 = 0, rows = 0, accT = 0;
#pragma unroll
  for (int ee = 0; ee < NE; ++ee) {
    const int c = cnt[ee];
    const int nt = (c + 255) >> 8;
    if (dId >= accT && dId < accT + nt) {
      e = ee; r0 = (dId - accT) * 256;
      rows = c - r0; if (rows > 256) rows = 256;
    }
    accT += nt;
  }
  if (e < 0) return;   // block-uniform exit, before any barrier

  // ring-3: A 3x16KB + B 3x16KB + lists 2KB = 98KB -> 1 block/CU, 8 waves
  __shared__ __align__(16) unsigned short As[3][256 * 32];
  __shared__ __align__(16) unsigned short Bs[3][256 * 32];
  __shared__ int   tid_s[256];
  __shared__ float w_s[256];

  const int tid = threadIdx.x;
  if (tid < 256) {
    if (tid < rows) {
      tid_s[tid] = listTok[e * TOK + r0 + tid];
      w_s[tid]   = listW [e * TOK + r0 + tid];
    } else {
      tid_s[tid] = 0;   // safe dummy row (token 0) — never stored
      w_s[tid]   = 0.0f;
    }
  }
  __syncthreads();      // drains vmcnt -> counted region starts clean

  const int w    = tid >> 6;           // wave 0..7
  const int lane = tid & 63;
  // Staging: per call, wave w covers 16 rows (4 lanes/row). Call pairs split
  // the 256 rows as [w*16 .. w*16+15] and [128 + w*16 ..]. Lane l -> row
  // base+(l>>2), slot l&3; pre-swizzled global quarter = (l&3)^((l>>3)&3).
  const int qsrc = (lane & 3) ^ ((lane >> 3) & 3);
  const int lr   = lane >> 2;
  const unsigned short* srcA0 = xb + (size_t)(tid_s[      w * 16 + lr] >> 1) * DIM + qsrc * 8;
  const unsigned short* srcA1 = xb + (size_t)(tid_s[128 + w * 16 + lr] >> 1) * DIM + qsrc * 8;
  const size_t bbase = ((size_t)e * DIM + cT * 256) * DIM;
  const unsigned short* srcB0 = Wt + bbase + (size_t)(      w * 16 + lr) * DIM + qsrc * 8;
  const unsigned short* srcB1 = Wt + bbase + (size_t)(128 + w * 16 + lr) * DIM + qsrc * 8;

  const int wr = w >> 2, wc = w & 3;   // 2M x 4N wave grid, 128x64 out each
  const int mrow = lane & 15;
  const int qg   = lane >> 4;
  const int s8   = (qg ^ ((mrow >> 1) & 3)) * 8;   // verified conflict-free
  const unsigned rdA2 = (unsigned)(((wr * 128 + mrow) * 32 + s8) * 2);  // bytes
  const unsigned rdB2 = (unsigned)(((wc * 64 + mrow) * 32 + s8) * 2);   // bytes
  const unsigned asOff = lds_off(&As[0][0]);
  const unsigned bsOff = lds_off(&Bs[0][0]);

  f32x4 acc[8][4];
#pragma unroll
  for (int i = 0; i < 8; ++i)
#pragma unroll
    for (int j = 0; j < 4; ++j)
      acc[i][j] = {0.f, 0.f, 0.f, 0.f};

  // prologue: tiles 0,1 -> slots 0,1 (8 calls); vmcnt(4): tile 0 resident,
  // tile 1's 4 calls in flight
  STG(0, 0);
  STG(1, 1);
  WAITVM(4);
  __builtin_amdgcn_s_barrier();

  int sC = 0, sS = 2;
#pragma unroll 1
  for (int kt = 0; kt < 32; ++kt) {
    if (kt < 30) STG(kt + 2, sS);      // slot held tile kt-1: consumed
    CMP(sC);
    if (kt < 30) {
      WAITVM(4);                       // tile kt+1 resident; kt+2 in flight
      __builtin_amdgcn_s_barrier();
    } else if (kt == 30) {
      WAITVM(0);                       // drain tile 31
      __builtin_amdgcn_s_barrier();
    }
    sC = (sC == 2) ? 0 : sC + 1;
    sS = (sS == 2) ? 0 : sS + 1;
  }

  // epilogue: C/D map col=lane&15, row=(lane>>4)*4+r
  const int colBase = cT * 256 + wc * 64 + mrow;
  float bias[4];
#pragma unroll
  for (int nt = 0; nt < 4; ++nt)
    bias[nt] = eb[(size_t)e * DIM + colBase + nt * 16];
#pragma unroll
  for (int mt = 0; mt < 8; ++mt) {
#pragma unroll
    for (int r = 0; r < 4; ++r) {
      const int rloc = wr * 128 + mt * 16 + (lane >> 4) * 4 + r;
      if (rloc < rows) {
        const int tk    = tid_s[rloc];
        const float wgt = w_s[rloc];
        __half* dst = yslot + ((size_t)(tk & 1) * TOK + (size_t)(tk >> 1)) * DIM;
#pragma unroll
        for (int nt = 0; nt < 4; ++nt)
          dst[colBase + nt * 16] = __float2half(wgt * (acc[mt][nt][r] + bias[nt]));
      }
    }
  }
}

__global__ __launch_bounds__(256) void combine(
    const __half* __restrict__ y0, const __half* __restrict__ y1,
    float4* __restrict__ out)
{
  const size_t i = (size_t)blockIdx.x * 256 + threadIdx.x;  // float4 index
  const ushort4 ua = ((const ushort4*)y0)[i];
  const ushort4 ub = ((const ushort4*)y1)[i];
  const __half* ah = (const __half*)&ua;
  const __half* bh = (const __half*)&ub;
  float4 o;
  o.x = __half2float(ah[0]) + __half2float(bh[0]);
  o.y = __half2float(ah[1]) + __half2float(bh[1]);
  o.z = __half2float(ah[2]) + __half2float(bh[2]);
  o.w = __half2float(ah[3]) + __half2float(bh[3]);
  out[i] = o;
}

extern "C" void kernel_launch(void* const* d_in, const int* in_sizes, int n_in,
                              void* d_out, int out_size, void* d_ws, size_t ws_size,
                              hipStream_t stream)
{
  const float* x  = (const float*)d_in[0];
  const float* gW = (const float*)d_in[1];
  const float* gb = (const float*)d_in[2];
  const float* eW = (const float*)d_in[3];
  const float* eb = (const float*)d_in[4];
  float* out = (float*)d_out;

  char* p = (char*)d_ws;
  unsigned short* xb = (unsigned short*)p;  p += (size_t)TOK * DIM * 2;       // 16 MB
  unsigned short* Wt = (unsigned short*)p;  p += (size_t)NE * DIM * DIM * 2;  // 16 MB
  __half* yslot = (__half*)p;               p += (size_t)2 * TOK * DIM * 2;   // 32 MB
  int* cnt = (int*)p;                       p += 256;
  int* listTok = (int*)p;                   p += (size_t)NE * TOK * 4;
  float* listW = (float*)p;                 p += (size_t)NE * TOK * 4;

  // eSel/wSel alias the head of yslot: consumed by scatter_kernel BEFORE
  // moe_gemm overwrites yslot (stream-ordered).
  int*   eSel = (int*)yslot;                        // TOK*2 ints = 64 KB
  float* wSel = (float*)((char*)yslot + TOK * 8);   // TOK*2 floats = 64 KB

  gate_transpose<<<4096, 256, 0, stream>>>(x, gW, gb, xb, eSel, wSel, cnt, eW, Wt);
  scatter_kernel<<<TOK / 256, 256, 0, stream>>>(eSel, wSel, cnt, listTok, listW);
  moe_gemm<<<NT * NCT, 512, 0, stream>>>(xb, Wt, eb, cnt, listTok, listW, yslot);
  combine<<<TOK * DIM / 4 / 256, 256, 0, stream>>>(
      yslot, yslot + (size_t)TOK * DIM, (float4*)out);
}